// Round 2
// baseline (206.927 us; speedup 1.0000x reference)
//
#include <hip/hip_runtime.h>

// Elementwise over B=8388608 rows of X:(B,4) f32 -> out:(B,2) f32.
// Memory-bound floor: 128 MiB in + 64 MiB out = 201 MB -> ~30.5 us @ 6.6 TB/s
// (the harness's own fillBuffer dispatches measure 6.6-6.7 TB/s on this box).
// Key change vs 201us baseline: precise libm sinf/cosf (full range reduction,
// ~hundreds of VALU ops/row) -> hardware v_sin/v_cos (__sinf/__cosf).
// Args are <= ~21 rad (~3.4 revolutions), well inside accurate hw-trig domain;
// added error ~4e-5 << passing absmax 7.8e-3.
// Two rows per thread: 2x float4 loads, one 16B nontemporal store.

// native clang vector type: __builtin_nontemporal_store requires it
// (HIP's float4 is a struct wrapper and is rejected).
typedef float vfloat4 __attribute__((ext_vector_type(4)));

__device__ __forceinline__ void cgp_row(float4 x, float c0, float c1,
                                        float& n7, float& n8) {
    float n4 = x.x * x.y;
    float n5 = __sinf(n4 + c0);        // v_sin_f32 path
    float n6 = x.z * x.w;
    n7 = fmaf(n5, n6, __sinf(x.z));
    n8 = fmaf(__cosf(n7), c1, x.x);    // v_cos_f32 path
}

__global__ __launch_bounds__(256) void cgp_kernel(const float4* __restrict__ X,
                                                  const float* __restrict__ ephs,
                                                  vfloat4* __restrict__ out2,
                                                  float2* __restrict__ out1,
                                                  int nPairs, int B) {
    int i = blockIdx.x * blockDim.x + threadIdx.x;

    const float c0 = ephs[0];   // wave-uniform -> s_load
    const float c1 = ephs[1];

    if (i < nPairs) {
        // rows 2i and 2i+1: two 16B loads (complementary halves of the same
        // cache lines across the wave), one coalesced 16B store.
        float4 a = X[2 * i];
        float4 b = X[2 * i + 1];

        float n7a, n8a, n7b, n8b;
        cgp_row(a, c0, c1, n7a, n8a);
        cgp_row(b, c0, c1, n7b, n8b);

        // write-once output: nontemporal hint, don't evict X from L2/L3
        vfloat4 r = {n7a, n8a, n7b, n8b};
        __builtin_nontemporal_store(r, &out2[i]);
    } else if (i == nPairs && (B & 1)) {
        // defensive odd-B tail (B is even for this problem)
        float4 a = X[B - 1];
        float n7, n8;
        cgp_row(a, c0, c1, n7, n8);
        out1[B - 1] = make_float2(n7, n8);
    }
}

extern "C" void kernel_launch(void* const* d_in, const int* in_sizes, int n_in,
                              void* d_out, int out_size, void* d_ws, size_t ws_size,
                              hipStream_t stream) {
    const float4* X  = (const float4*)d_in[0];
    const float* eph = (const float*)d_in[1];
    int B = in_sizes[0] / 4;            // in_sizes counts f32 elements; B = 8388608
    int nPairs = B >> 1;                // 4194304 threads, 16384 blocks

    int block = 256;
    int work = nPairs + (B & 1);
    int grid = (work + block - 1) / block;
    cgp_kernel<<<grid, block, 0, stream>>>(X, eph, (vfloat4*)d_out,
                                           (float2*)d_out, nPairs, B);
}